// Round 2
// baseline (353.395 us; speedup 1.0000x reference)
//
#include <hip/hip_runtime.h>
#include <hip/hip_bf16.h>

// WindowAttention fused kernel v5 (MI355X / gfx950)
// One block = one window. 4 waves, wave = head everywhere.
// v5 changes vs v3:
//  - x staged ONCE into LDS as bf16 (swizzled); phase-1 fragments re-read from
//    LDS per tile instead of being held in 64 VGPRs (v3's compiler remat was
//    re-loading from GLOBAL and re-converting 6x -> VALU bloat, VGPR=64 tell)
//  - K moved to registers (pkK) like V; kb built in phase 2 via the same
//    8-shuffle+select redistribution as va/pk (pairs-along-channel layout)
//  - LDS: X/O aliased @0 (16KB) + Q @16K (16KB) = 32KB, launch_bounds(256,5)
//    -> 5 blocks/CU (160KB exact)
//  - softmax max/sum as depth-4 trees; mask rows loaded before score MFMAs

#define T49  49
#define CDIM 128
#define NW   64
#define SCALEF 0.17677669529663689f   // 1/sqrt(32)

typedef short bf16x8 __attribute__((ext_vector_type(8)));
typedef float f32x4  __attribute__((ext_vector_type(4)));

union B8 { unsigned int u[4]; bf16x8 v; };

__device__ __forceinline__ unsigned int pk2(float a, float b) {
  __hip_bfloat162 h = __float22bfloat162_rn(make_float2(a, b));
  unsigned int u;
  __builtin_memcpy(&u, &h, 4);
  return u;
}

__device__ __forceinline__ unsigned short f2bf(float f) {
  unsigned int u = __builtin_bit_cast(unsigned int, f);
  u += 0x7fffu + ((u >> 16) & 1u);
  return (unsigned short)(u >> 16);
}

// prep: bf16 weights + padded mask maskp[64][64 q][64 key], pads = -1e30
__global__ void prep_kernel(const float* __restrict__ wq, const float* __restrict__ wp,
                            const float* __restrict__ mask,
                            short* __restrict__ wq_bf, short* __restrict__ wp_bf,
                            float* __restrict__ maskp) {
  const int i = blockIdx.x * 256 + threadIdx.x;      // grid covers 262144
  const int w = i >> 12, q = (i >> 6) & 63, k = i & 63;
  float mv = -1e30f;
  if (q < T49 && k < T49) mv = mask[(w * T49 + q) * T49 + k];
  maskp[i] = mv;
  if (i < 3 * CDIM * CDIM) wq_bf[i] = (short)f2bf(wq[i]);
  if (i < CDIM * CDIM)     wp_bf[i] = (short)f2bf(wp[i]);
}

__global__ __launch_bounds__(256, 5)
void winattn_kernel(const float* __restrict__ x, const float* __restrict__ maskp,
                    const float* __restrict__ b_qkv, const float* __restrict__ b_proj,
                    const short* __restrict__ wq, const short* __restrict__ wp,
                    float* __restrict__ out) {
  // LDS (32 KB -> 5 blocks/CU):
  //  X  [64 t][128 ch] bf16 @ 0      (16 KB) swz: cbyte ^ ((t&7)<<4); dead after ph1
  //  O  [64 t][128 ch] bf16 @ 0      (16 KB) aliases X; swz: chbyte ^ ((t&7)<<5)
  //  Q  [4h][64 t][32 d] bf16 @ 16384 (16 KB) swz: dbyte ^ ((t&3)<<4)
  //  K, V: registers only (pkK, pkV)
  __shared__ __align__(16) char smem[32768];
  constexpr int XO_BASE = 0, Q_BASE = 16384;

  const int bw    = blockIdx.x;
  const int wv    = threadIdx.x >> 6;
  const int lane  = threadIdx.x & 63;
  const int g     = lane >> 4;
  const int j16   = lane & 15;
  const int wmask = bw & (NW - 1);

  // ---------------- Phase 0: stage x -> LDS bf16, swizzled ----------------
  {
    const int tid = threadIdx.x;
    const int t   = tid >> 2;            // 0..63
    const int c0  = (tid & 3) * 32;      // 32 consecutive channels per thread
    char* wb = smem + XO_BASE + t * 256;
    const int swz = (t & 7) << 4;
    if (t < T49) {
      const float* p = x + (size_t)bw * (T49 * CDIM) + t * CDIM + c0;
#pragma unroll
      for (int q = 0; q < 4; ++q) {
        const float4 v0 = *(const float4*)(p + q * 8);
        const float4 v1 = *(const float4*)(p + q * 8 + 4);
        uint4 u;
        u.x = pk2(v0.x, v0.y); u.y = pk2(v0.z, v0.w);
        u.z = pk2(v1.x, v1.y); u.w = pk2(v1.z, v1.w);
        *(uint4*)(wb + ((c0 * 2 + q * 16) ^ swz)) = u;
      }
    } else {
#pragma unroll
      for (int q = 0; q < 4; ++q)
        *(uint4*)(wb + ((c0 * 2 + q * 16) ^ swz)) = make_uint4(0u, 0u, 0u, 0u);
    }
  }
  __syncthreads();

  // x fragment from LDS: serves as A (natural, m=t) AND B (swapped, n=t)
  auto XF = [&](int tt, int kt) -> bf16x8 {
    const int t = tt * 16 + j16;
    return *(const bf16x8*)(smem + XO_BASE + t * 256 +
                            ((kt * 64 + g * 16) ^ ((t & 7) << 4)));
  };

  // ---------------- Phase 1: QKV (wave wv = head wv) ----------------
  unsigned int pkK[2][4][2];  // [d-tile vi][tt][pair]: pairs along channel (swapped D[c][t])
  unsigned int pkV[2][4][2];  // [d-tile vi][tt][pair]: pairs along token   (natural D[t][c])

#pragma unroll
  for (int ni = 0; ni < 6; ++ni) {
    const int ct = (ni < 2) ? (wv * 2 + ni)
                 : (ni < 4) ? (8 + wv * 2 + (ni - 2))
                            : (16 + wv * 2 + (ni - 4));
    bf16x8 wf[4];                                     // w frag: row c=ct*16+j16, k=kt*32+g*8..+7
#pragma unroll
    for (int kt = 0; kt < 4; ++kt)
      wf[kt] = *(const bf16x8*)(wq + (ct * 16 + j16) * CDIM + kt * 32 + g * 8);

    if (ni < 4) {
      // swapped: D[c][t]; lane holds 4 consecutive channels at token t
      const int   c0 = ct * 16 + g * 4;
      const float4 b4 = *(const float4*)(b_qkv + c0);
      if (ni < 2) {
        // Q -> LDS (read back by same wave in phase 2)
        char* base = smem + Q_BASE + wv * 4096;
        const int d0 = c0 & 31;
#pragma unroll
        for (int tt = 0; tt < 4; ++tt) {
          f32x4 acc = {0.f, 0.f, 0.f, 0.f};
#pragma unroll
          for (int kt = 0; kt < 4; ++kt)
            acc = __builtin_amdgcn_mfma_f32_16x16x32_bf16(wf[kt], XF(tt, kt), acc, 0, 0, 0);
          const int t = tt * 16 + j16;
          const uint2 w2 = make_uint2(pk2(fmaf(acc[0], SCALEF, b4.x * SCALEF),
                                          fmaf(acc[1], SCALEF, b4.y * SCALEF)),
                                      pk2(fmaf(acc[2], SCALEF, b4.z * SCALEF),
                                          fmaf(acc[3], SCALEF, b4.w * SCALEF)));
          *(uint2*)(base + t * 64 + ((d0 * 2) ^ ((t & 3) << 4))) = w2;
        }
      } else {
        // K -> registers
        const int vi = ni - 2;
#pragma unroll
        for (int tt = 0; tt < 4; ++tt) {
          f32x4 acc = {0.f, 0.f, 0.f, 0.f};
#pragma unroll
          for (int kt = 0; kt < 4; ++kt)
            acc = __builtin_amdgcn_mfma_f32_16x16x32_bf16(wf[kt], XF(tt, kt), acc, 0, 0, 0);
          pkK[vi][tt][0] = pk2(acc[0] + b4.x, acc[1] + b4.y);
          pkK[vi][tt][1] = pk2(acc[2] + b4.z, acc[3] + b4.w);
        }
      }
    } else {
      // V natural: D[t][c] -> registers (pairs along token)
      const int   vi   = ni - 4;
      const float bias = b_qkv[ct * 16 + j16];
#pragma unroll
      for (int tt = 0; tt < 4; ++tt) {
        f32x4 acc = {0.f, 0.f, 0.f, 0.f};
#pragma unroll
        for (int kt = 0; kt < 4; ++kt)
          acc = __builtin_amdgcn_mfma_f32_16x16x32_bf16(XF(tt, kt), wf[kt], acc, 0, 0, 0);
        pkV[vi][tt][0] = pk2(acc[0] + bias, acc[1] + bias);
        pkV[vi][tt][1] = pk2(acc[2] + bias, acc[3] + bias);
      }
    }
  }
  // NO barrier: phase 2 reads only this wave's own Q (LDS) and pkK (regs).

  // ---------------- Phase 2: S^T = K·Q^T, mask, softmax (wave = head) ----------------
  const int h    = wv;
  const int gh   = g >> 1;
  const int srcA = (((2 * g    ) & 3) << 4) | j16;
  const int srcB = (((2 * g + 1) & 3) << 4) | j16;

  unsigned int pk[4][4][2];   // [key-tile mt][q-tile nt][pair]: bf16 pairs of P^T
  {
    // kb[mt] elem e = K[t=mt*16+j16][d=g*8+e]; source pkK[g>>1][mt][.] at
    // lane ((2g+(e>>2))&3)*16+j16, pair (e&3)>>1 -- same pattern as va build.
    bf16x8 kb[4];
#pragma unroll
    for (int mt = 0; mt < 4; ++mt) {
      const unsigned int a0 = (unsigned)__shfl((int)pkK[0][mt][0], srcA, 64);
      const unsigned int a1 = (unsigned)__shfl((int)pkK[0][mt][1], srcA, 64);
      const unsigned int c0 = (unsigned)__shfl((int)pkK[1][mt][0], srcA, 64);
      const unsigned int c1 = (unsigned)__shfl((int)pkK[1][mt][1], srcA, 64);
      const unsigned int b0 = (unsigned)__shfl((int)pkK[0][mt][0], srcB, 64);
      const unsigned int b1 = (unsigned)__shfl((int)pkK[0][mt][1], srcB, 64);
      const unsigned int d0 = (unsigned)__shfl((int)pkK[1][mt][0], srcB, 64);
      const unsigned int d1 = (unsigned)__shfl((int)pkK[1][mt][1], srcB, 64);
      B8 u;
      u.u[0] = gh ? c0 : a0;
      u.u[1] = gh ? c1 : a1;
      u.u[2] = gh ? d0 : b0;
      u.u[3] = gh ? d1 : b1;
      kb[mt] = u.v;
    }
    const char* Qb = smem + Q_BASE + h * 4096;
#pragma unroll
    for (int nt = 0; nt < 4; ++nt) {
      const int q = nt * 16 + j16;
      const bf16x8 qb = *(const bf16x8*)(Qb + q * 64 + ((g * 16) ^ ((q & 3) << 4)));
      const float* mp = maskp + (wmask * 64 + q) * 64 + g * 4;
      float4 m4[4];
#pragma unroll
      for (int mt = 0; mt < 4; ++mt) m4[mt] = *(const float4*)(mp + mt * 16);
      const f32x4 zero = {0.f, 0.f, 0.f, 0.f};
      float v[4][4];
#pragma unroll
      for (int mt = 0; mt < 4; ++mt) {
        const f32x4 s = __builtin_amdgcn_mfma_f32_16x16x32_bf16(kb[mt], qb, zero, 0, 0, 0);
        v[mt][0] = s[0] + m4[mt].x; v[mt][1] = s[1] + m4[mt].y;
        v[mt][2] = s[2] + m4[mt].z; v[mt][3] = s[3] + m4[mt].w;
      }
      // depth-4 max tree
      float mr[8];
#pragma unroll
      for (int mt = 0; mt < 4; ++mt) {
        mr[2 * mt]     = fmaxf(v[mt][0], v[mt][1]);
        mr[2 * mt + 1] = fmaxf(v[mt][2], v[mt][3]);
      }
      float mx = fmaxf(fmaxf(fmaxf(mr[0], mr[1]), fmaxf(mr[2], mr[3])),
                       fmaxf(fmaxf(mr[4], mr[5]), fmaxf(mr[6], mr[7])));
      mx = fmaxf(mx, __shfl_xor(mx, 16, 64));
      mx = fmaxf(mx, __shfl_xor(mx, 32, 64));
      // exp + depth-4 sum tree
      float sr[8];
#pragma unroll
      for (int mt = 0; mt < 4; ++mt) {
        v[mt][0] = __expf(v[mt][0] - mx); v[mt][1] = __expf(v[mt][1] - mx);
        v[mt][2] = __expf(v[mt][2] - mx); v[mt][3] = __expf(v[mt][3] - mx);
        sr[2 * mt]     = v[mt][0] + v[mt][1];
        sr[2 * mt + 1] = v[mt][2] + v[mt][3];
      }
      float sum = ((sr[0] + sr[1]) + (sr[2] + sr[3])) + ((sr[4] + sr[5]) + (sr[6] + sr[7]));
      sum += __shfl_xor(sum, 16, 64);
      sum += __shfl_xor(sum, 32, 64);
      const float inv = 1.0f / sum;
#pragma unroll
      for (int mt = 0; mt < 4; ++mt) {
        pk[mt][nt][0] = pk2(v[mt][0] * inv, v[mt][1] * inv);
        pk[mt][nt][1] = pk2(v[mt][2] * inv, v[mt][3] * inv);
      }
    }
  }
  __syncthreads();            // all X reads (ph1) + Q reads (ph2) done before O overwrites X

  // ---------------- Phase 3: O^T = V^T · P^T (wave = head) ----------------
  {
    // V^T A-frag redistribution from pkV (register-only):
    // va[dt][ks] elem e wants V[key=ks*32+8g+e][d=dt*16+j16]: source tile
    // tt = 2ks + (g>>1), lane (2g+(e>>2))&3 group, pair (e&3)>>1.
    bf16x8 va[2][2];
#pragma unroll
    for (int dt = 0; dt < 2; ++dt)
#pragma unroll
      for (int ks = 0; ks < 2; ++ks) {
        const unsigned int a0  = (unsigned)__shfl((int)pkV[dt][2 * ks    ][0], srcA, 64);
        const unsigned int a0h = (unsigned)__shfl((int)pkV[dt][2 * ks + 1][0], srcA, 64);
        const unsigned int a1  = (unsigned)__shfl((int)pkV[dt][2 * ks    ][1], srcA, 64);
        const unsigned int a1h = (unsigned)__shfl((int)pkV[dt][2 * ks + 1][1], srcA, 64);
        const unsigned int b0  = (unsigned)__shfl((int)pkV[dt][2 * ks    ][0], srcB, 64);
        const unsigned int b0h = (unsigned)__shfl((int)pkV[dt][2 * ks + 1][0], srcB, 64);
        const unsigned int b1  = (unsigned)__shfl((int)pkV[dt][2 * ks    ][1], srcB, 64);
        const unsigned int b1h = (unsigned)__shfl((int)pkV[dt][2 * ks + 1][1], srcB, 64);
        B8 u;
        u.u[0] = gh ? a0h : a0;
        u.u[1] = gh ? a1h : a1;
        u.u[2] = gh ? b0h : b0;
        u.u[3] = gh ? b1h : b1;
        va[dt][ks] = u.v;
      }

    char* Ob = smem + XO_BASE;
#pragma unroll
    for (int nt = 0; nt < 4; ++nt) {
      f32x4 oacc[2] = {{0.f,0.f,0.f,0.f},{0.f,0.f,0.f,0.f}};
#pragma unroll
      for (int ks = 0; ks < 2; ++ks) {
        const unsigned int p00 = (unsigned)__shfl((int)pk[2*ks  ][nt][0], srcA, 64);
        const unsigned int p10 = (unsigned)__shfl((int)pk[2*ks+1][nt][0], srcA, 64);
        const unsigned int p01 = (unsigned)__shfl((int)pk[2*ks  ][nt][1], srcA, 64);
        const unsigned int p11 = (unsigned)__shfl((int)pk[2*ks+1][nt][1], srcA, 64);
        const unsigned int q00 = (unsigned)__shfl((int)pk[2*ks  ][nt][0], srcB, 64);
        const unsigned int q10 = (unsigned)__shfl((int)pk[2*ks+1][nt][0], srcB, 64);
        const unsigned int q01 = (unsigned)__shfl((int)pk[2*ks  ][nt][1], srcB, 64);
        const unsigned int q11 = (unsigned)__shfl((int)pk[2*ks+1][nt][1], srcB, 64);
        B8 bf;
        bf.u[0] = gh ? p10 : p00;
        bf.u[1] = gh ? p11 : p01;
        bf.u[2] = gh ? q10 : q00;
        bf.u[3] = gh ? q11 : q01;
#pragma unroll
        for (int dt = 0; dt < 2; ++dt)
          oacc[dt] = __builtin_amdgcn_mfma_f32_16x16x32_bf16(va[dt][ks], bf.v, oacc[dt], 0, 0, 0);
      }
      // D[d][q]: 4 regs = consecutive channels -> b64 store into O[t][ch]
      const int t = nt * 16 + j16;
      const int sw = (t & 7) << 5;
#pragma unroll
      for (int dt = 0; dt < 2; ++dt) {
        const int ch0 = h * 32 + dt * 16 + g * 4;
        const uint2 w2 = make_uint2(pk2(oacc[dt][0], oacc[dt][1]),
                                    pk2(oacc[dt][2], oacc[dt][3]));
        *(uint2*)(Ob + t * 256 + ((ch0 * 2) ^ sw)) = w2;
      }
    }
  }
  __syncthreads();

  // ---------------- Phase 4: out = O @ wp^T + b ----------------
  {
    const char* Ob = smem + XO_BASE;
    bf16x8 oa[4][4];
#pragma unroll
    for (int mt = 0; mt < 4; ++mt) {
      const int t = mt * 16 + j16;
      const int sw = (t & 7) << 5;
#pragma unroll
      for (int kt = 0; kt < 4; ++kt)
        oa[mt][kt] = *(const bf16x8*)(Ob + t * 256 + ((kt * 64 + g * 16) ^ sw));
    }
    float* ob = out + (size_t)bw * (T49 * CDIM);
#pragma unroll
    for (int ntl = 0; ntl < 2; ++ntl) {
      const int c = (wv * 2 + ntl) * 16 + j16;
      bf16x8 bfr[4];
#pragma unroll
      for (int kt = 0; kt < 4; ++kt)
        bfr[kt] = *(const bf16x8*)(wp + c * CDIM + kt * 32 + g * 8);
      const float bias = b_proj[c];
#pragma unroll
      for (int mt = 0; mt < 4; ++mt) {
        f32x4 acc = {0.f, 0.f, 0.f, 0.f};
#pragma unroll
        for (int kt = 0; kt < 4; ++kt)
          acc = __builtin_amdgcn_mfma_f32_16x16x32_bf16(oa[mt][kt], bfr[kt], acc, 0, 0, 0);
#pragma unroll
        for (int r = 0; r < 4; ++r) {
          const int t = mt * 16 + g * 4 + r;
          if (t < T49) ob[t * CDIM + c] = acc[r] + bias;
        }
      }
    }
  }
}

extern "C" void kernel_launch(void* const* d_in, const int* in_sizes, int n_in,
                              void* d_out, int out_size, void* d_ws, size_t ws_size,
                              hipStream_t stream) {
  const float* x      = (const float*)d_in[0];
  const float* mask   = (const float*)d_in[1];
  const float* w_qkv  = (const float*)d_in[2];
  const float* b_qkv  = (const float*)d_in[3];
  const float* w_proj = (const float*)d_in[4];
  const float* b_proj = (const float*)d_in[5];
  float* out = (float*)d_out;

  float* maskp = (float*)d_ws;                       // 64*64*64 f32 = 1 MB
  short* wq_bf = (short*)((char*)d_ws + 64*64*64*4); // 96 KB
  short* wp_bf = wq_bf + 3 * CDIM * CDIM;            // 32 KB

  hipLaunchKernelGGL(prep_kernel, dim3(1024), dim3(256), 0, stream,
                     w_qkv, w_proj, mask, wq_bf, wp_bf, maskp);
  hipLaunchKernelGGL(winattn_kernel, dim3(8192), dim3(256), 0, stream,
                     x, maskp, b_qkv, b_proj, wq_bf, wp_bf, out);
}